// Round 16
// baseline (225.934 us; speedup 1.0000x reference)
//
#include <hip/hip_runtime.h>

typedef __attribute__((ext_vector_type(4))) float f32x4;
typedef __attribute__((ext_vector_type(8))) short bf16x8;

#define MFMA(a, b, c) __builtin_amdgcn_mfma_f32_16x16x32_bf16(a, b, c, 0, 0, 0)
// WAR-hazard shield (R13-proven)
#define NOPS asm volatile("s_nop 7\ns_nop 7\ns_nop 7\ns_nop 7" ::: "memory")

static __device__ __forceinline__ short rnebf(float x) {
  union { float f; unsigned u; } v; v.f = x;
  return (short)((v.u + 0x7FFFu + ((v.u >> 16) & 1u)) >> 16);
}
static __device__ __forceinline__ float bf2f(short h) {
  union { unsigned u; float f; } v; v.u = ((unsigned)(unsigned short)h) << 16;
  return v.f;
}
// RNE hi + RNE lo (R14-proven)
static __device__ __forceinline__ void split2(float x, short& hi, short& lo) {
  hi = rnebf(x);
  lo = rnebf(x - bf2f(hi));
}

// ---------------- prep: pack 8 weights as hi/lo B-fragments ----------------
__global__ void prep_w(const float* __restrict__ W0, const float* __restrict__ W1,
                       const float* __restrict__ W2, const float* __restrict__ W3,
                       const float* __restrict__ W4, const float* __restrict__ W5,
                       const float* __restrict__ W6, const float* __restrict__ W7,
                       short* __restrict__ ws) {
  const float* W[8] = {W0, W1, W2, W3, W4, W5, W6, W7};
  int t = blockIdx.x * 256 + threadIdx.x;
  int lane = t & 63, fragid = (t >> 6) & 7, mat = t >> 9;
  const float* Wm = W[mat];
  int ct = fragid >> 1, kh = fragid & 1;
  int wcol = ct * 16 + (lane & 15);
  int k0 = kh * 32 + ((lane >> 4) << 3);
  bf16x8 vh, vl;
#pragma unroll
  for (int j = 0; j < 8; ++j) {
    short h, l;
    split2(Wm[(k0 + j) * 64 + wcol], h, l);
    vh[j] = h; vl[j] = l;
  }
  size_t base = ((size_t)(mat * 16) + fragid) * 512 + lane * 8;
  *(bf16x8*)(ws + base) = vh;
  *(bf16x8*)(ws + base + 4096) = vl;
}

struct BF { bf16x8 h[4][2], l[4][2]; };

static __device__ __forceinline__ void loadB(const short* __restrict__ ws, int mat, int lane,
                                             BF& B) {
#pragma unroll
  for (int ct = 0; ct < 4; ++ct)
#pragma unroll
    for (int kh = 0; kh < 2; ++kh) {
      B.h[ct][kh] = *(const bf16x8*)(ws + ((size_t)(mat * 16) + ct * 2 + kh) * 512 + lane * 8);
      B.l[ct][kh] = *(const bf16x8*)(ws + ((size_t)(mat * 16 + 8) + ct * 2 + kh) * 512 + lane * 8);
    }
}

// fenced MFMA cluster (R13-proven)
static __device__ __forceinline__ void cluster(const bf16x8 (&ah)[2], const bf16x8 (&al)[2],
                                               const BF& B, f32x4 (&acc)[4]) {
  __builtin_amdgcn_sched_barrier(0);
#pragma unroll
  for (int ct = 0; ct < 4; ++ct)
#pragma unroll
    for (int kh = 0; kh < 2; ++kh) {
      acc[ct] = MFMA(ah[kh], B.h[ct][kh], acc[ct]);
      acc[ct] = MFMA(al[kh], B.h[ct][kh], acc[ct]);
      acc[ct] = MFMA(ah[kh], B.l[ct][kh], acc[ct]);
    }
  __builtin_amdgcn_sched_barrier(0);
  NOPS;
}

// swizzled stride-64 plane load/store (HW-verified R6; plane = 8192 B)
static __device__ __forceinline__ void ldM(const short* __restrict__ M, int ph, int arow,
                                           int lane, bf16x8 (&ah)[2], bf16x8 (&al)[2]) {
  int swz = (arow & 7) << 4;
#pragma unroll
  for (int kh = 0; kh < 2; ++kh) {
    int ab = (arow * 128 + kh * 64 + ((lane >> 4) << 4)) ^ swz;
    ah[kh] = *(const bf16x8*)((const char*)M + ph * 8192 + ab);
    al[kh] = *(const bf16x8*)((const char*)M + (ph + 1) * 8192 + ab);
  }
}
static __device__ __forceinline__ void stM(short* __restrict__ M, int p, int n, int w, float x) {
  short h, l;
  split2(x, h, l);
  int ab = (n * 128 + w * 2) ^ ((n & 7) << 4);
  *(short*)((char*)M + p * 8192 + ab) = h;
  *(short*)((char*)M + (p + 1) * 8192 + ab) = l;
}

// ---------------- fused kernel: 64 rows/block, 256 threads ----------------
// Single barrier after phase 0; all later LDS traffic is wave-private rows
// (stM writes and ldM reads both touch only rows [wid*16, wid*16+16)), so
// waves free-run and overlap each other's B-load/tp-load latency with MFMA.
__global__ __launch_bounds__(256, 2) void fused_tp(
    const float* __restrict__ x1, const float* __restrict__ edge,
    const float* __restrict__ tp, const float* __restrict__ node,
    const short* __restrict__ ws, float* __restrict__ out) {
  __shared__ short lds_s[8 * 4096];   // 8 swizzled half-planes, 64 KB
  __shared__ float cst[64 * 6];       // e0,e1x,e1y,e1z,c2a
  const int t = threadIdx.x;
  const int R0 = blockIdx.x * 64;
  const int lane = t & 63;

  BF B;
  loadB(ws, 0, lane, B);  // W_sc_s — issued at entry, lands during phase 0

  // ---- phase 0: stage ksc-scaled x1 -> planes s(0,1) vx(2,3) vy(4,5) vz(6,7) ----
  {
    int c = t;
    int plane_hi, u;
    if (c < 64) { plane_hi = 0; u = c; }
    else { int q = c - 64; u = q / 3; int m = q - u * 3; plane_hi = 2 + 2 * m; }
    char* phi = (char*)lds_s + plane_hi * 8192;
    char* plo = phi + 8192;
    const float* xc = x1 + (size_t)R0 * 256 + c;
#pragma unroll 8
    for (int i = 0; i < 64; ++i) {
      float ksc = 0.125f * node[R0 + i];
      short h, l;
      split2(ksc * xc[(size_t)i * 256], h, l);
      int ab = (i * 128 + u * 2) ^ ((i & 7) << 4);
      *(short*)(phi + ab) = h;
      *(short*)(plo + ab) = l;
    }
    if (t < 64) {
      f32x4 e = *(const f32x4*)(edge + (size_t)(R0 + t) * 4);
      float a = node[R0 + t];
      float* cr = cst + t * 6;
      cr[0] = e[0]; cr[1] = e[1]; cr[2] = e[2]; cr[3] = e[3];
      cr[4] = 0.08838834764831845f * a;  // c2a = kp/ksc
    }
  }
  __syncthreads();  // the ONLY barrier

  const int wid = t >> 6;
  const int r0 = wid * 16;
  const int lg = lane >> 4;
  const int arow = r0 + (lane & 15);
  const f32x4 z = {0.f, 0.f, 0.f, 0.f};

  f32x4 outS[4], outV[3][4], s0v[4], v0v[3][4];
#pragma unroll
  for (int ct = 0; ct < 4; ++ct) { outS[ct] = z; s0v[ct] = z; }
#pragma unroll
  for (int m = 0; m < 3; ++m)
#pragma unroll
    for (int ct = 0; ct < 4; ++ct) { outV[m][ct] = z; v0v[m][ct] = z; }

  // ---- stage 1: 8 clusters, 4 B-loads ----
  {
    bf16x8 ah[2], al[2];
    ldM(lds_s, 0, arow, lane, ah, al);           // s' = ksc*s
    cluster(ah, al, B, outS);                    // += ksc*scs
    loadB(ws, 1, lane, B);                       // W_lin0_s
    cluster(ah, al, B, s0v);                     // s0' = ksc*s0
    loadB(ws, 2, lane, B);                       // W_sc_v (x3 reuse)
#pragma unroll
    for (int m = 0; m < 3; ++m) {
      ldM(lds_s, 2 + 2 * m, arow, lane, ah, al);
      cluster(ah, al, B, outV[m]);               // += ksc*scv_m
    }
    loadB(ws, 3, lane, B);                       // W_lin0_v (x3 reuse)
#pragma unroll
    for (int m = 0; m < 3; ++m) {
      ldM(lds_s, 2 + 2 * m, arow, lane, ah, al);
      cluster(ah, al, B, v0v[m]);                // v0' = ksc*v0
    }
  }

  // ---- phase 2a (wave-private): kp*mA -> (0,1), kp*e1m*mB -> (2,3),(4,5),(6,7) ----
  loadB(ws, 4, lane, B);                         // W_lin_A — lands during mid VALU
#pragma unroll
  for (int reg = 0; reg < 4; ++reg) {
    int n = r0 + (lg << 2) + reg;
    const float* cr = cst + n * 6;
    float e0 = cr[0], e1x = cr[1], e1y = cr[2], e1z = cr[3], c2a = cr[4];
    const float* tr = tp + (size_t)(R0 + n) * 256;
#pragma unroll
    for (int ct = 0; ct < 4; ++ct) {
      int w = ct * 16 + (lane & 15);
      float t0 = c2a * s0v[ct][reg];             // kp*s0
      float wa = tr[w], wb = tr[64 + w];
      stM(lds_s, 0, n, w, wa * t0 * e0);
      float bmul = wb * t0;
      stM(lds_s, 2, n, w, bmul * e1x);
      stM(lds_s, 4, n, w, bmul * e1y);
      stM(lds_s, 6, n, w, bmul * e1z);
    }
  }

  // ---- stage 2a: WA on mA -> outS ; WB on mB_m -> outV[m] ----
  {
    bf16x8 ah[2], al[2];
    ldM(lds_s, 0, arow, lane, ah, al);
    cluster(ah, al, B, outS);
    loadB(ws, 6, lane, B);                       // W_lin_B (x3 reuse)
#pragma unroll
    for (int m = 0; m < 3; ++m) {
      ldM(lds_s, 2 + 2 * m, arow, lane, ah, al);
      cluster(ah, al, B, outV[m]);
    }
  }

  // ---- phase 2b (wave-private): kp*mD -> (0,1), kp*mC_m -> (2,3),(4,5),(6,7) ----
  loadB(ws, 5, lane, B);                         // W_lin_D — lands during mid VALU
#pragma unroll
  for (int reg = 0; reg < 4; ++reg) {
    int n = r0 + (lg << 2) + reg;
    const float* cr = cst + n * 6;
    float e0 = cr[0], e1x = cr[1], e1y = cr[2], e1z = cr[3], c2a = cr[4];
    const float* tr = tp + (size_t)(R0 + n) * 256;
#pragma unroll
    for (int ct = 0; ct < 4; ++ct) {
      int w = ct * 16 + (lane & 15);
      float kv0 = c2a * v0v[0][ct][reg];
      float kv1 = c2a * v0v[1][ct][reg];
      float kv2 = c2a * v0v[2][ct][reg];
      float wc = tr[128 + w], wd = tr[192 + w];
      stM(lds_s, 0, n, w, wd * (kv0 * e1x + kv1 * e1y + kv2 * e1z) * 0.5773502691896258f);
      stM(lds_s, 2, n, w, wc * kv0 * e0);
      stM(lds_s, 4, n, w, wc * kv1 * e0);
      stM(lds_s, 6, n, w, wc * kv2 * e0);
    }
  }

  // ---- stage 2b: WD on mD -> outS ; WC on mC_m -> outV[m] ----
  {
    bf16x8 ah[2], al[2];
    ldM(lds_s, 0, arow, lane, ah, al);
    cluster(ah, al, B, outS);
    loadB(ws, 7, lane, B);                       // W_lin_C (x3 reuse)
#pragma unroll
    for (int m = 0; m < 3; ++m) {
      ldM(lds_s, 2 + 2 * m, arow, lane, ah, al);
      cluster(ah, al, B, outV[m]);
    }
  }

  // ---- epilogue: bare store ----
#pragma unroll
  for (int reg = 0; reg < 4; ++reg) {
    int n = r0 + (lg << 2) + reg;
    float* orow = out + (size_t)(R0 + n) * 256;
#pragma unroll
    for (int ct = 0; ct < 4; ++ct) {
      int w = ct * 16 + (lane & 15);
      orow[w] = outS[ct][reg];
      float* vp = orow + 64 + 3 * w;
      vp[0] = outV[0][ct][reg];
      vp[1] = outV[1][ct][reg];
      vp[2] = outV[2][ct][reg];
    }
  }
}

extern "C" void kernel_launch(void* const* d_in, const int* in_sizes, int n_in,
                              void* d_out, int out_size, void* d_ws, size_t ws_size,
                              hipStream_t stream) {
  const float* x1   = (const float*)d_in[0];
  const float* edge = (const float*)d_in[1];
  const float* tp   = (const float*)d_in[2];
  const float* node = (const float*)d_in[3];
  short* ws = (short*)d_ws;  // 128 KiB
  int n = in_sizes[0] / 256;

  // mats: 0=W_sc_s 1=W_lin0_s 2=W_sc_v 3=W_lin0_v 4=W_lin_A 5=W_lin_D 6=W_lin_B 7=W_lin_C
  prep_w<<<16, 256, 0, stream>>>(
      (const float*)d_in[6], (const float*)d_in[4],
      (const float*)d_in[7], (const float*)d_in[5],
      (const float*)d_in[8], (const float*)d_in[9],
      (const float*)d_in[10], (const float*)d_in[11], ws);

  fused_tp<<<n / 64, 256, 0, stream>>>(x1, edge, tp, node, ws, (float*)d_out);
}

// Round 17
// 222.862 us; speedup vs baseline: 1.0138x; 1.0138x over previous
//
#include <hip/hip_runtime.h>

typedef __attribute__((ext_vector_type(4))) float f32x4;
typedef __attribute__((ext_vector_type(8))) short bf16x8;

#define MFMA(a, b, c) __builtin_amdgcn_mfma_f32_16x16x32_bf16(a, b, c, 0, 0, 0)
// WAR-hazard shield (R13-proven)
#define NOPS asm volatile("s_nop 7\ns_nop 7\ns_nop 7\ns_nop 7" ::: "memory")

static __device__ __forceinline__ short rnebf(float x) {
  union { float f; unsigned u; } v; v.f = x;
  return (short)((v.u + 0x7FFFu + ((v.u >> 16) & 1u)) >> 16);
}
static __device__ __forceinline__ float bf2f(short h) {
  union { unsigned u; float f; } v; v.u = ((unsigned)(unsigned short)h) << 16;
  return v.f;
}
// RNE hi + RNE lo (R14-proven)
static __device__ __forceinline__ void split2(float x, short& hi, short& lo) {
  hi = rnebf(x);
  lo = rnebf(x - bf2f(hi));
}

// ---------------- prep: pack 8 weights as hi/lo B-fragments (layout unchanged) ----------------
__global__ void prep_w(const float* __restrict__ W0, const float* __restrict__ W1,
                       const float* __restrict__ W2, const float* __restrict__ W3,
                       const float* __restrict__ W4, const float* __restrict__ W5,
                       const float* __restrict__ W6, const float* __restrict__ W7,
                       short* __restrict__ ws) {
  const float* W[8] = {W0, W1, W2, W3, W4, W5, W6, W7};
  int t = blockIdx.x * 256 + threadIdx.x;
  int lane = t & 63, fragid = (t >> 6) & 7, mat = t >> 9;
  const float* Wm = W[mat];
  int ct = fragid >> 1, kh = fragid & 1;
  int wcol = ct * 16 + (lane & 15);
  int k0 = kh * 32 + ((lane >> 4) << 3);
  bf16x8 vh, vl;
#pragma unroll
  for (int j = 0; j < 8; ++j) {
    short h, l;
    split2(Wm[(k0 + j) * 64 + wcol], h, l);
    vh[j] = h; vl[j] = l;
  }
  size_t base = ((size_t)(mat * 16) + fragid) * 512 + lane * 8;
  *(bf16x8*)(ws + base) = vh;
  *(bf16x8*)(ws + base + 4096) = vl;
}

// half-width B: this wave's 2 ct-tiles only (32 VGPR)
struct BF2 { bf16x8 h[2][2], l[2][2]; };

static __device__ __forceinline__ void loadB(const short* __restrict__ ws, int mat, int lane,
                                             int ch, BF2& B) {
#pragma unroll
  for (int cti = 0; cti < 2; ++cti)
#pragma unroll
    for (int kh = 0; kh < 2; ++kh) {
      int ct = 2 * ch + cti;
      B.h[cti][kh] = *(const bf16x8*)(ws + ((size_t)(mat * 16) + ct * 2 + kh) * 512 + lane * 8);
      B.l[cti][kh] = *(const bf16x8*)(ws + ((size_t)(mat * 16 + 8) + ct * 2 + kh) * 512 + lane * 8);
    }
}

// fenced MFMA cluster: 12 MFMAs over this wave's 2 ct-tiles
static __device__ __forceinline__ void cluster(const bf16x8 (&ah)[2], const bf16x8 (&al)[2],
                                               const BF2& B, f32x4 (&acc)[2]) {
  __builtin_amdgcn_sched_barrier(0);
#pragma unroll
  for (int cti = 0; cti < 2; ++cti)
#pragma unroll
    for (int kh = 0; kh < 2; ++kh) {
      acc[cti] = MFMA(ah[kh], B.h[cti][kh], acc[cti]);
      acc[cti] = MFMA(al[kh], B.h[cti][kh], acc[cti]);
      acc[cti] = MFMA(ah[kh], B.l[cti][kh], acc[cti]);
    }
  __builtin_amdgcn_sched_barrier(0);
  NOPS;
}

// swizzled stride-64 plane load/store (HW-verified R6; half-plane = 8192 B)
static __device__ __forceinline__ void ldM(const short* __restrict__ M, int ph, int arow,
                                           int lane, bf16x8 (&ah)[2], bf16x8 (&al)[2]) {
  int swz = (arow & 7) << 4;
#pragma unroll
  for (int kh = 0; kh < 2; ++kh) {
    int ab = (arow * 128 + kh * 64 + ((lane >> 4) << 4)) ^ swz;
    ah[kh] = *(const bf16x8*)((const char*)M + ph * 8192 + ab);
    al[kh] = *(const bf16x8*)((const char*)M + (ph + 1) * 8192 + ab);
  }
}
static __device__ __forceinline__ void stM(short* __restrict__ M, int p, int n, int w, float x) {
  short h, l;
  split2(x, h, l);
  int ab = (n * 128 + w * 2) ^ ((n & 7) << 4);
  *(short*)((char*)M + p * 8192 + ab) = h;
  *(short*)((char*)M + (p + 1) * 8192 + ab) = l;
}

// ---------------- fused kernel: 64 rows/block, 512 threads (8 waves) ----------------
// Wave pair shares 16 rows; ch = wid&1 splits the 4 ct column-tiles 2+2.
// R15 barrier structure (barriers also fence regalloc live ranges — R16 lesson).
__global__ __launch_bounds__(512, 2) void fused_tp(
    const float* __restrict__ x1, const float* __restrict__ edge,
    const float* __restrict__ tp, const float* __restrict__ node,
    const short* __restrict__ ws, float* __restrict__ out) {
  __shared__ short lds_s[8 * 4096];   // 8 swizzled half-planes, 64 KB
  __shared__ float cst[64 * 6];       // e0,e1x,e1y,e1z,c2a
  const int t = threadIdx.x;
  const int R0 = blockIdx.x * 64;
  const int lane = t & 63;

  // ---- phase 0: stage ksc-scaled x1; 512 threads: col c = t&255, row-half t>>8 ----
  {
    int c = t & 255;
    int half = t >> 8;
    int plane_hi, u;
    if (c < 64) { plane_hi = 0; u = c; }
    else { int q = c - 64; u = q / 3; int m = q - u * 3; plane_hi = 2 + 2 * m; }
    char* phi = (char*)lds_s + plane_hi * 8192;
    char* plo = phi + 8192;
    const float* xc = x1 + (size_t)R0 * 256 + c;
#pragma unroll 8
    for (int ii = 0; ii < 32; ++ii) {
      int i = half * 32 + ii;
      float ksc = 0.125f * node[R0 + i];
      short h, l;
      split2(ksc * xc[(size_t)i * 256], h, l);
      int ab = (i * 128 + u * 2) ^ ((i & 7) << 4);
      *(short*)(phi + ab) = h;
      *(short*)(plo + ab) = l;
    }
    if (t < 64) {
      f32x4 e = *(const f32x4*)(edge + (size_t)(R0 + t) * 4);
      float a = node[R0 + t];
      float* cr = cst + t * 6;
      cr[0] = e[0]; cr[1] = e[1]; cr[2] = e[2]; cr[3] = e[3];
      cr[4] = 0.08838834764831845f * a;  // c2a = kp/ksc
    }
  }
  __syncthreads();

  const int wid = t >> 6;
  const int ch = wid & 1;          // column half: ct in {2ch, 2ch+1}
  const int r0 = (wid >> 1) * 16;  // row group
  const int lg = lane >> 4;
  const int arow = r0 + (lane & 15);
  const f32x4 z = {0.f, 0.f, 0.f, 0.f};

  f32x4 outS[2], outV[3][2], s0v[2], v0v[3][2];
#pragma unroll
  for (int c2 = 0; c2 < 2; ++c2) { outS[c2] = z; s0v[c2] = z; }
#pragma unroll
  for (int m = 0; m < 3; ++m)
#pragma unroll
    for (int c2 = 0; c2 < 2; ++c2) { outV[m][c2] = z; v0v[m][c2] = z; }

  // ---- stage 1: 8 clusters, 4 B-loads ----
  {
    BF2 B;
    bf16x8 ah[2], al[2];
    loadB(ws, 0, lane, ch, B);                   // W_sc_s
    ldM(lds_s, 0, arow, lane, ah, al);           // s' = ksc*s
    cluster(ah, al, B, outS);
    loadB(ws, 1, lane, ch, B);                   // W_lin0_s
    cluster(ah, al, B, s0v);
    loadB(ws, 2, lane, ch, B);                   // W_sc_v (x3 reuse)
#pragma unroll
    for (int m = 0; m < 3; ++m) {
      ldM(lds_s, 2 + 2 * m, arow, lane, ah, al);
      cluster(ah, al, B, outV[m]);
    }
    loadB(ws, 3, lane, ch, B);                   // W_lin0_v (x3 reuse)
#pragma unroll
    for (int m = 0; m < 3; ++m) {
      ldM(lds_s, 2 + 2 * m, arow, lane, ah, al);
      cluster(ah, al, B, v0v[m]);
    }
  }
  __syncthreads();

  // ---- phase 2a: kp*mA -> (0,1), kp*e1m*mB -> (2,3),(4,5),(6,7); this wave's columns ----
#pragma unroll
  for (int reg = 0; reg < 4; ++reg) {
    int n = r0 + (lg << 2) + reg;
    const float* cr = cst + n * 6;
    float e0 = cr[0], e1x = cr[1], e1y = cr[2], e1z = cr[3], c2a = cr[4];
    const float* tr = tp + (size_t)(R0 + n) * 256;
#pragma unroll
    for (int cti = 0; cti < 2; ++cti) {
      int w = (2 * ch + cti) * 16 + (lane & 15);
      float t0 = c2a * s0v[cti][reg];            // kp*s0
      float wa = tr[w], wb = tr[64 + w];
      stM(lds_s, 0, n, w, wa * t0 * e0);
      float bmul = wb * t0;
      stM(lds_s, 2, n, w, bmul * e1x);
      stM(lds_s, 4, n, w, bmul * e1y);
      stM(lds_s, 6, n, w, bmul * e1z);
    }
  }
  __syncthreads();

  // ---- stage 2a: WA on mA -> outS ; WB on mB_m -> outV[m] ----
  {
    BF2 B;
    bf16x8 ah[2], al[2];
    loadB(ws, 4, lane, ch, B);                   // W_lin_A
    ldM(lds_s, 0, arow, lane, ah, al);
    cluster(ah, al, B, outS);
    loadB(ws, 6, lane, ch, B);                   // W_lin_B (x3 reuse)
#pragma unroll
    for (int m = 0; m < 3; ++m) {
      ldM(lds_s, 2 + 2 * m, arow, lane, ah, al);
      cluster(ah, al, B, outV[m]);
    }
  }
  __syncthreads();

  // ---- phase 2b: kp*mD -> (0,1), kp*mC_m -> (2,3),(4,5),(6,7) ----
#pragma unroll
  for (int reg = 0; reg < 4; ++reg) {
    int n = r0 + (lg << 2) + reg;
    const float* cr = cst + n * 6;
    float e0 = cr[0], e1x = cr[1], e1y = cr[2], e1z = cr[3], c2a = cr[4];
    const float* tr = tp + (size_t)(R0 + n) * 256;
#pragma unroll
    for (int cti = 0; cti < 2; ++cti) {
      int w = (2 * ch + cti) * 16 + (lane & 15);
      float kv0 = c2a * v0v[0][cti][reg];
      float kv1 = c2a * v0v[1][cti][reg];
      float kv2 = c2a * v0v[2][cti][reg];
      float wc = tr[128 + w], wd = tr[192 + w];
      stM(lds_s, 0, n, w, wd * (kv0 * e1x + kv1 * e1y + kv2 * e1z) * 0.5773502691896258f);
      stM(lds_s, 2, n, w, wc * kv0 * e0);
      stM(lds_s, 4, n, w, wc * kv1 * e0);
      stM(lds_s, 6, n, w, wc * kv2 * e0);
    }
  }
  __syncthreads();

  // ---- stage 2b: WD on mD -> outS ; WC on mC_m -> outV[m] ----
  {
    BF2 B;
    bf16x8 ah[2], al[2];
    loadB(ws, 5, lane, ch, B);                   // W_lin_D
    ldM(lds_s, 0, arow, lane, ah, al);
    cluster(ah, al, B, outS);
    loadB(ws, 7, lane, ch, B);                   // W_lin_C (x3 reuse)
#pragma unroll
    for (int m = 0; m < 3; ++m) {
      ldM(lds_s, 2 + 2 * m, arow, lane, ah, al);
      cluster(ah, al, B, outV[m]);
    }
  }

  // ---- epilogue: bare store of this wave's columns ----
#pragma unroll
  for (int reg = 0; reg < 4; ++reg) {
    int n = r0 + (lg << 2) + reg;
    float* orow = out + (size_t)(R0 + n) * 256;
#pragma unroll
    for (int cti = 0; cti < 2; ++cti) {
      int w = (2 * ch + cti) * 16 + (lane & 15);
      orow[w] = outS[cti][reg];
      float* vp = orow + 64 + 3 * w;
      vp[0] = outV[0][cti][reg];
      vp[1] = outV[1][cti][reg];
      vp[2] = outV[2][cti][reg];
    }
  }
}

extern "C" void kernel_launch(void* const* d_in, const int* in_sizes, int n_in,
                              void* d_out, int out_size, void* d_ws, size_t ws_size,
                              hipStream_t stream) {
  const float* x1   = (const float*)d_in[0];
  const float* edge = (const float*)d_in[1];
  const float* tp   = (const float*)d_in[2];
  const float* node = (const float*)d_in[3];
  short* ws = (short*)d_ws;  // 128 KiB
  int n = in_sizes[0] / 256;

  // mats: 0=W_sc_s 1=W_lin0_s 2=W_sc_v 3=W_lin0_v 4=W_lin_A 5=W_lin_D 6=W_lin_B 7=W_lin_C
  prep_w<<<16, 256, 0, stream>>>(
      (const float*)d_in[6], (const float*)d_in[4],
      (const float*)d_in[7], (const float*)d_in[5],
      (const float*)d_in[8], (const float*)d_in[9],
      (const float*)d_in[10], (const float*)d_in[11], ws);

  fused_tp<<<n / 64, 512, 0, stream>>>(x1, edge, tp, node, ws, (float*)d_out);
}

// Round 18
// 179.245 us; speedup vs baseline: 1.2605x; 1.2433x over previous
//
#include <hip/hip_runtime.h>

typedef __attribute__((ext_vector_type(4))) float f32x4;
typedef __attribute__((ext_vector_type(8))) short bf16x8;

#define MFMA(a, b, c) __builtin_amdgcn_mfma_f32_16x16x32_bf16(a, b, c, 0, 0, 0)
// WAR-hazard shield (R13-proven)
#define NOPS asm volatile("s_nop 7\ns_nop 7\ns_nop 7\ns_nop 7" ::: "memory")

static __device__ __forceinline__ short rnebf(float x) {
  union { float f; unsigned u; } v; v.f = x;
  return (short)((v.u + 0x7FFFu + ((v.u >> 16) & 1u)) >> 16);
}
static __device__ __forceinline__ float bf2f(short h) {
  union { unsigned u; float f; } v; v.u = ((unsigned)(unsigned short)h) << 16;
  return v.f;
}
// RNE hi + RNE lo (R14-proven)
static __device__ __forceinline__ void split2(float x, short& hi, short& lo) {
  hi = rnebf(x);
  lo = rnebf(x - bf2f(hi));
}

// ---------------- prep: pack 8 weights as hi/lo B-fragments (layout unchanged) ----------------
__global__ void prep_w(const float* __restrict__ W0, const float* __restrict__ W1,
                       const float* __restrict__ W2, const float* __restrict__ W3,
                       const float* __restrict__ W4, const float* __restrict__ W5,
                       const float* __restrict__ W6, const float* __restrict__ W7,
                       short* __restrict__ ws) {
  const float* W[8] = {W0, W1, W2, W3, W4, W5, W6, W7};
  int t = blockIdx.x * 256 + threadIdx.x;
  int lane = t & 63, fragid = (t >> 6) & 7, mat = t >> 9;
  const float* Wm = W[mat];
  int ct = fragid >> 1, kh = fragid & 1;
  int wcol = ct * 16 + (lane & 15);
  int k0 = kh * 32 + ((lane >> 4) << 3);
  bf16x8 vh, vl;
#pragma unroll
  for (int j = 0; j < 8; ++j) {
    short h, l;
    split2(Wm[(k0 + j) * 64 + wcol], h, l);
    vh[j] = h; vl[j] = l;
  }
  size_t base = ((size_t)(mat * 16) + fragid) * 512 + lane * 8;
  *(bf16x8*)(ws + base) = vh;
  *(bf16x8*)(ws + base + 4096) = vl;
}

// half-width B: this wave's 2 ct-tiles (32 VGPR)
struct BF2 { bf16x8 h[2][2], l[2][2]; };

static __device__ __forceinline__ void loadB(const short* __restrict__ ws, int mat, int lane,
                                             int ch, BF2& B) {
#pragma unroll
  for (int cti = 0; cti < 2; ++cti)
#pragma unroll
    for (int kh = 0; kh < 2; ++kh) {
      int ct = 2 * ch + cti;
      B.h[cti][kh] = *(const bf16x8*)(ws + ((size_t)(mat * 16) + ct * 2 + kh) * 512 + lane * 8);
      B.l[cti][kh] = *(const bf16x8*)(ws + ((size_t)(mat * 16 + 8) + ct * 2 + kh) * 512 + lane * 8);
    }
}

// fenced MFMA cluster: 12 MFMAs over this wave's 2 ct-tiles
static __device__ __forceinline__ void cluster(const bf16x8 (&ah)[2], const bf16x8 (&al)[2],
                                               const BF2& B, f32x4 (&acc)[2]) {
  __builtin_amdgcn_sched_barrier(0);
#pragma unroll
  for (int cti = 0; cti < 2; ++cti)
#pragma unroll
    for (int kh = 0; kh < 2; ++kh) {
      acc[cti] = MFMA(ah[kh], B.h[cti][kh], acc[cti]);
      acc[cti] = MFMA(al[kh], B.h[cti][kh], acc[cti]);
      acc[cti] = MFMA(ah[kh], B.l[cti][kh], acc[cti]);
    }
  __builtin_amdgcn_sched_barrier(0);
  NOPS;
}

// swizzled [32][64] plane load/store (half-plane = 4096 B)
static __device__ __forceinline__ void ldM(const short* __restrict__ M, int ph, int arow,
                                           int lane, bf16x8 (&ah)[2], bf16x8 (&al)[2]) {
  int swz = (arow & 7) << 4;
#pragma unroll
  for (int kh = 0; kh < 2; ++kh) {
    int ab = (arow * 128 + kh * 64 + ((lane >> 4) << 4)) ^ swz;
    ah[kh] = *(const bf16x8*)((const char*)M + ph * 4096 + ab);
    al[kh] = *(const bf16x8*)((const char*)M + (ph + 1) * 4096 + ab);
  }
}
static __device__ __forceinline__ void stM(short* __restrict__ M, int p, int n, int w, float x) {
  short h, l;
  split2(x, h, l);
  int ab = (n * 128 + w * 2) ^ ((n & 7) << 4);
  *(short*)((char*)M + p * 4096 + ab) = h;
  *(short*)((char*)M + (p + 1) * 4096 + ab) = l;
}

// ---------------- fused kernel: 32 rows/block, 256 threads (4 waves) ----------------
// wave = (row-group wid>>1: 16 rows) x (column-half wid&1: ct in {2ch,2ch+1}).
// Per-wave state ~140 regs -> 3 waves/SIMD; LDS 33.5 KB. R15 barrier placement.
__global__ __launch_bounds__(256, 3) void fused_tp(
    const float* __restrict__ x1, const float* __restrict__ edge,
    const float* __restrict__ tp, const float* __restrict__ node,
    const short* __restrict__ ws, float* __restrict__ out) {
  __shared__ short lds_s[8 * 2048];   // 8 swizzled half-planes [32][64], 32 KB
  __shared__ float cst[32 * 6];       // e0,e1x,e1y,e1z,c2a
  const int t = threadIdx.x;
  const int R0 = blockIdx.x * 32;
  const int lane = t & 63;

  // ---- phase 0: stage ksc-scaled x1 -> planes s(0,1) vx(2,3) vy(4,5) vz(6,7) ----
  {
    int c = t;
    int plane_hi, u;
    if (c < 64) { plane_hi = 0; u = c; }
    else { int q = c - 64; u = q / 3; int m = q - u * 3; plane_hi = 2 + 2 * m; }
    char* phi = (char*)lds_s + plane_hi * 4096;
    char* plo = phi + 4096;
    const float* xc = x1 + (size_t)R0 * 256 + c;
#pragma unroll 8
    for (int i = 0; i < 32; ++i) {
      float ksc = 0.125f * node[R0 + i];
      short h, l;
      split2(ksc * xc[(size_t)i * 256], h, l);
      int ab = (i * 128 + u * 2) ^ ((i & 7) << 4);
      *(short*)(phi + ab) = h;
      *(short*)(plo + ab) = l;
    }
    if (t < 32) {
      f32x4 e = *(const f32x4*)(edge + (size_t)(R0 + t) * 4);
      float a = node[R0 + t];
      float* cr = cst + t * 6;
      cr[0] = e[0]; cr[1] = e[1]; cr[2] = e[2]; cr[3] = e[3];
      cr[4] = 0.08838834764831845f * a;  // c2a = kp/ksc
    }
  }
  __syncthreads();

  const int wid = t >> 6;
  const int ch = wid & 1;          // column half: ct in {2ch, 2ch+1}
  const int r0 = (wid >> 1) * 16;  // row group (0 or 16)
  const int lg = lane >> 4;
  const int arow = r0 + (lane & 15);
  const f32x4 z = {0.f, 0.f, 0.f, 0.f};

  f32x4 outS[2], outV[3][2], s0v[2], v0v[3][2];
#pragma unroll
  for (int c2 = 0; c2 < 2; ++c2) { outS[c2] = z; s0v[c2] = z; }
#pragma unroll
  for (int m = 0; m < 3; ++m)
#pragma unroll
    for (int c2 = 0; c2 < 2; ++c2) { outV[m][c2] = z; v0v[m][c2] = z; }

  // ---- stage 1: 8 clusters, 4 B-loads ----
  {
    BF2 B;
    bf16x8 ah[2], al[2];
    loadB(ws, 0, lane, ch, B);                   // W_sc_s
    ldM(lds_s, 0, arow, lane, ah, al);           // s' = ksc*s
    cluster(ah, al, B, outS);
    loadB(ws, 1, lane, ch, B);                   // W_lin0_s
    cluster(ah, al, B, s0v);
    loadB(ws, 2, lane, ch, B);                   // W_sc_v (x3 reuse)
#pragma unroll
    for (int m = 0; m < 3; ++m) {
      ldM(lds_s, 2 + 2 * m, arow, lane, ah, al);
      cluster(ah, al, B, outV[m]);
    }
    loadB(ws, 3, lane, ch, B);                   // W_lin0_v (x3 reuse)
#pragma unroll
    for (int m = 0; m < 3; ++m) {
      ldM(lds_s, 2 + 2 * m, arow, lane, ah, al);
      cluster(ah, al, B, v0v[m]);
    }
  }
  __syncthreads();

  // ---- phase 2a: kp*mA -> (0,1), kp*e1m*mB -> (2,3),(4,5),(6,7); own columns ----
#pragma unroll
  for (int reg = 0; reg < 4; ++reg) {
    int n = r0 + (lg << 2) + reg;
    const float* cr = cst + n * 6;
    float e0 = cr[0], e1x = cr[1], e1y = cr[2], e1z = cr[3], c2a = cr[4];
    const float* tr = tp + (size_t)(R0 + n) * 256;
#pragma unroll
    for (int cti = 0; cti < 2; ++cti) {
      int w = (2 * ch + cti) * 16 + (lane & 15);
      float t0 = c2a * s0v[cti][reg];            // kp*s0
      float wa = tr[w], wb = tr[64 + w];
      stM(lds_s, 0, n, w, wa * t0 * e0);
      float bmul = wb * t0;
      stM(lds_s, 2, n, w, bmul * e1x);
      stM(lds_s, 4, n, w, bmul * e1y);
      stM(lds_s, 6, n, w, bmul * e1z);
    }
  }
  __syncthreads();

  // ---- stage 2a: WA on mA -> outS ; WB on mB_m -> outV[m] ----
  {
    BF2 B;
    bf16x8 ah[2], al[2];
    loadB(ws, 4, lane, ch, B);                   // W_lin_A
    ldM(lds_s, 0, arow, lane, ah, al);
    cluster(ah, al, B, outS);
    loadB(ws, 6, lane, ch, B);                   // W_lin_B (x3 reuse)
#pragma unroll
    for (int m = 0; m < 3; ++m) {
      ldM(lds_s, 2 + 2 * m, arow, lane, ah, al);
      cluster(ah, al, B, outV[m]);
    }
  }
  __syncthreads();

  // ---- phase 2b: kp*mD -> (0,1), kp*mC_m -> (2,3),(4,5),(6,7) ----
#pragma unroll
  for (int reg = 0; reg < 4; ++reg) {
    int n = r0 + (lg << 2) + reg;
    const float* cr = cst + n * 6;
    float e0 = cr[0], e1x = cr[1], e1y = cr[2], e1z = cr[3], c2a = cr[4];
    const float* tr = tp + (size_t)(R0 + n) * 256;
#pragma unroll
    for (int cti = 0; cti < 2; ++cti) {
      int w = (2 * ch + cti) * 16 + (lane & 15);
      float kv0 = c2a * v0v[0][cti][reg];
      float kv1 = c2a * v0v[1][cti][reg];
      float kv2 = c2a * v0v[2][cti][reg];
      float wc = tr[128 + w], wd = tr[192 + w];
      stM(lds_s, 0, n, w, wd * (kv0 * e1x + kv1 * e1y + kv2 * e1z) * 0.5773502691896258f);
      stM(lds_s, 2, n, w, wc * kv0 * e0);
      stM(lds_s, 4, n, w, wc * kv1 * e0);
      stM(lds_s, 6, n, w, wc * kv2 * e0);
    }
  }
  __syncthreads();

  // ---- stage 2b: WD on mD -> outS ; WC on mC_m -> outV[m] ----
  {
    BF2 B;
    bf16x8 ah[2], al[2];
    loadB(ws, 5, lane, ch, B);                   // W_lin_D
    ldM(lds_s, 0, arow, lane, ah, al);
    cluster(ah, al, B, outS);
    loadB(ws, 7, lane, ch, B);                   // W_lin_C (x3 reuse)
#pragma unroll
    for (int m = 0; m < 3; ++m) {
      ldM(lds_s, 2 + 2 * m, arow, lane, ah, al);
      cluster(ah, al, B, outV[m]);
    }
  }

  // ---- epilogue: bare store of own columns ----
#pragma unroll
  for (int reg = 0; reg < 4; ++reg) {
    int n = r0 + (lg << 2) + reg;
    float* orow = out + (size_t)(R0 + n) * 256;
#pragma unroll
    for (int cti = 0; cti < 2; ++cti) {
      int w = (2 * ch + cti) * 16 + (lane & 15);
      orow[w] = outS[cti][reg];
      float* vp = orow + 64 + 3 * w;
      vp[0] = outV[0][cti][reg];
      vp[1] = outV[1][cti][reg];
      vp[2] = outV[2][cti][reg];
    }
  }
}

extern "C" void kernel_launch(void* const* d_in, const int* in_sizes, int n_in,
                              void* d_out, int out_size, void* d_ws, size_t ws_size,
                              hipStream_t stream) {
  const float* x1   = (const float*)d_in[0];
  const float* edge = (const float*)d_in[1];
  const float* tp   = (const float*)d_in[2];
  const float* node = (const float*)d_in[3];
  short* ws = (short*)d_ws;  // 128 KiB
  int n = in_sizes[0] / 256;

  // mats: 0=W_sc_s 1=W_lin0_s 2=W_sc_v 3=W_lin0_v 4=W_lin_A 5=W_lin_D 6=W_lin_B 7=W_lin_C
  prep_w<<<16, 256, 0, stream>>>(
      (const float*)d_in[6], (const float*)d_in[4],
      (const float*)d_in[7], (const float*)d_in[5],
      (const float*)d_in[8], (const float*)d_in[9],
      (const float*)d_in[10], (const float*)d_in[11], ws);

  fused_tp<<<n / 32, 256, 0, stream>>>(x1, edge, tp, node, ws, (float*)d_out);
}

// Round 19
// 164.407 us; speedup vs baseline: 1.3742x; 1.0903x over previous
//
#include <hip/hip_runtime.h>

typedef __attribute__((ext_vector_type(4))) float f32x4;
typedef __attribute__((ext_vector_type(8))) short bf16x8;

#define MFMA(a, b, c) __builtin_amdgcn_mfma_f32_16x16x32_bf16(a, b, c, 0, 0, 0)
// WAR-hazard shield (R13-proven)
#define NOPS asm volatile("s_nop 7\ns_nop 7\ns_nop 7\ns_nop 7" ::: "memory")

static __device__ __forceinline__ short rnebf(float x) {
  union { float f; unsigned u; } v; v.f = x;
  return (short)((v.u + 0x7FFFu + ((v.u >> 16) & 1u)) >> 16);
}
static __device__ __forceinline__ float bf2f(short h) {
  union { unsigned u; float f; } v; v.u = ((unsigned)(unsigned short)h) << 16;
  return v.f;
}
// RNE hi + RNE lo (R14-proven)
static __device__ __forceinline__ void split2(float x, short& hi, short& lo) {
  hi = rnebf(x);
  lo = rnebf(x - bf2f(hi));
}

// ---------------- prep: pack 8 weights as hi/lo B-fragments (layout unchanged) ----------------
__global__ void prep_w(const float* __restrict__ W0, const float* __restrict__ W1,
                       const float* __restrict__ W2, const float* __restrict__ W3,
                       const float* __restrict__ W4, const float* __restrict__ W5,
                       const float* __restrict__ W6, const float* __restrict__ W7,
                       short* __restrict__ ws) {
  const float* W[8] = {W0, W1, W2, W3, W4, W5, W6, W7};
  int t = blockIdx.x * 256 + threadIdx.x;
  int lane = t & 63, fragid = (t >> 6) & 7, mat = t >> 9;
  const float* Wm = W[mat];
  int ct = fragid >> 1, kh = fragid & 1;
  int wcol = ct * 16 + (lane & 15);
  int k0 = kh * 32 + ((lane >> 4) << 3);
  bf16x8 vh, vl;
#pragma unroll
  for (int j = 0; j < 8; ++j) {
    short h, l;
    split2(Wm[(k0 + j) * 64 + wcol], h, l);
    vh[j] = h; vl[j] = l;
  }
  size_t base = ((size_t)(mat * 16) + fragid) * 512 + lane * 8;
  *(bf16x8*)(ws + base) = vh;
  *(bf16x8*)(ws + base + 4096) = vl;
}

// half-width B: this wave's 2 ct-tiles (32 VGPR)
struct BF2 { bf16x8 h[2][2], l[2][2]; };

static __device__ __forceinline__ void loadB(const short* __restrict__ ws, int mat, int lane,
                                             int ch, BF2& B) {
#pragma unroll
  for (int cti = 0; cti < 2; ++cti)
#pragma unroll
    for (int kh = 0; kh < 2; ++kh) {
      int ct = 2 * ch + cti;
      B.h[cti][kh] = *(const bf16x8*)(ws + ((size_t)(mat * 16) + ct * 2 + kh) * 512 + lane * 8);
      B.l[cti][kh] = *(const bf16x8*)(ws + ((size_t)(mat * 16 + 8) + ct * 2 + kh) * 512 + lane * 8);
    }
}

// fenced MFMA cluster: 12 MFMAs over this wave's 2 ct-tiles
static __device__ __forceinline__ void cluster(const bf16x8 (&ah)[2], const bf16x8 (&al)[2],
                                               const BF2& B, f32x4 (&acc)[2]) {
  __builtin_amdgcn_sched_barrier(0);
#pragma unroll
  for (int cti = 0; cti < 2; ++cti)
#pragma unroll
    for (int kh = 0; kh < 2; ++kh) {
      acc[cti] = MFMA(ah[kh], B.h[cti][kh], acc[cti]);
      acc[cti] = MFMA(al[kh], B.h[cti][kh], acc[cti]);
      acc[cti] = MFMA(ah[kh], B.l[cti][kh], acc[cti]);
    }
  __builtin_amdgcn_sched_barrier(0);
  NOPS;
}

// swizzled [32][64] plane load/store (half-plane = 4096 B)
static __device__ __forceinline__ void ldM(const short* __restrict__ M, int ph, int arow,
                                           int lane, bf16x8 (&ah)[2], bf16x8 (&al)[2]) {
  int swz = (arow & 7) << 4;
#pragma unroll
  for (int kh = 0; kh < 2; ++kh) {
    int ab = (arow * 128 + kh * 64 + ((lane >> 4) << 4)) ^ swz;
    ah[kh] = *(const bf16x8*)((const char*)M + ph * 4096 + ab);
    al[kh] = *(const bf16x8*)((const char*)M + (ph + 1) * 4096 + ab);
  }
}
static __device__ __forceinline__ void stM(short* __restrict__ M, int p, int n, int w, float x) {
  short h, l;
  split2(x, h, l);
  int ab = (n * 128 + w * 2) ^ ((n & 7) << 4);
  *(short*)((char*)M + p * 4096 + ab) = h;
  *(short*)((char*)M + (p + 1) * 4096 + ab) = l;
}

// ---------------- fused kernel: 32 rows/block, 256 threads (4 waves) ----------------
// wave = (row-group wid>>1: 16 rows) x (column-half wid&1: ct in {2ch,2ch+1}).
// R19: deep-issue x1 staging; tp prefetched into regs (wa/wb before stage 1,
// wc/wd under stage 2a) so mid phases never stall on HBM.
__global__ __launch_bounds__(256, 3) void fused_tp(
    const float* __restrict__ x1, const float* __restrict__ edge,
    const float* __restrict__ tp, const float* __restrict__ node,
    const short* __restrict__ ws, float* __restrict__ out) {
  __shared__ short lds_s[8 * 2048];   // 8 swizzled half-planes [32][64], 32 KB
  __shared__ float cst[32 * 6];       // e0,e1x,e1y,e1z,c2a
  const int t = threadIdx.x;
  const int R0 = blockIdx.x * 32;
  const int lane = t & 63;
  const int wid = t >> 6;
  const int ch = wid & 1;          // column half: ct in {2ch, 2ch+1}
  const int r0 = (wid >> 1) * 16;  // row group (0 or 16)
  const int lg = lane >> 4;

  // ---- phase 0: deep-issue x1 + node into regs, then split/store pass ----
  {
    int c = t;
    int plane_hi, u;
    if (c < 64) { plane_hi = 0; u = c; }
    else { int q = c - 64; u = q / 3; int m = q - u * 3; plane_hi = 2 + 2 * m; }
    char* phi = (char*)lds_s + plane_hi * 4096;
    char* plo = phi + 4096;
    const float* xc = x1 + (size_t)R0 * 256 + c;
    float xv[32], nd[32];
#pragma unroll
    for (int i = 0; i < 32; ++i) xv[i] = xc[(size_t)i * 256];
#pragma unroll
    for (int i = 0; i < 32; ++i) nd[i] = node[R0 + i];
#pragma unroll
    for (int i = 0; i < 32; ++i) {
      short h, l;
      split2(0.125f * nd[i] * xv[i], h, l);
      int ab = (i * 128 + u * 2) ^ ((i & 7) << 4);
      *(short*)(phi + ab) = h;
      *(short*)(plo + ab) = l;
    }
    if (t < 32) {
      f32x4 e = *(const f32x4*)(edge + (size_t)(R0 + t) * 4);
      float a = node[R0 + t];
      float* cr = cst + t * 6;
      cr[0] = e[0]; cr[1] = e[1]; cr[2] = e[2]; cr[3] = e[3];
      cr[4] = 0.08838834764831845f * a;  // c2a = kp/ksc
    }
  }

  // ---- prefetch wa/wb (consumed in phase 2a; hidden under stage 1) ----
  float wa[2][4], wb[2][4];
#pragma unroll
  for (int reg = 0; reg < 4; ++reg) {
    int n = r0 + (lg << 2) + reg;
    const float* tr = tp + (size_t)(R0 + n) * 256;
#pragma unroll
    for (int cti = 0; cti < 2; ++cti) {
      int w = (2 * ch + cti) * 16 + (lane & 15);
      wa[cti][reg] = tr[w];
      wb[cti][reg] = tr[64 + w];
    }
  }
  __syncthreads();

  const int arow = r0 + (lane & 15);
  const f32x4 z = {0.f, 0.f, 0.f, 0.f};

  f32x4 outS[2], outV[3][2], s0v[2], v0v[3][2];
#pragma unroll
  for (int c2 = 0; c2 < 2; ++c2) { outS[c2] = z; s0v[c2] = z; }
#pragma unroll
  for (int m = 0; m < 3; ++m)
#pragma unroll
    for (int c2 = 0; c2 < 2; ++c2) { outV[m][c2] = z; v0v[m][c2] = z; }

  // ---- stage 1: 8 clusters, 4 B-loads ----
  {
    BF2 B;
    bf16x8 ah[2], al[2];
    loadB(ws, 0, lane, ch, B);                   // W_sc_s
    ldM(lds_s, 0, arow, lane, ah, al);           // s' = ksc*s
    cluster(ah, al, B, outS);
    loadB(ws, 1, lane, ch, B);                   // W_lin0_s
    cluster(ah, al, B, s0v);
    loadB(ws, 2, lane, ch, B);                   // W_sc_v (x3 reuse)
#pragma unroll
    for (int m = 0; m < 3; ++m) {
      ldM(lds_s, 2 + 2 * m, arow, lane, ah, al);
      cluster(ah, al, B, outV[m]);
    }
    loadB(ws, 3, lane, ch, B);                   // W_lin0_v (x3 reuse)
#pragma unroll
    for (int m = 0; m < 3; ++m) {
      ldM(lds_s, 2 + 2 * m, arow, lane, ah, al);
      cluster(ah, al, B, v0v[m]);
    }
  }
  __syncthreads();

  // ---- phase 2a: kp*mA -> (0,1), kp*e1m*mB -> (2,3),(4,5),(6,7); tp from regs ----
#pragma unroll
  for (int reg = 0; reg < 4; ++reg) {
    int n = r0 + (lg << 2) + reg;
    const float* cr = cst + n * 6;
    float e0 = cr[0], e1x = cr[1], e1y = cr[2], e1z = cr[3], c2a = cr[4];
#pragma unroll
    for (int cti = 0; cti < 2; ++cti) {
      int w = (2 * ch + cti) * 16 + (lane & 15);
      float t0 = c2a * s0v[cti][reg];            // kp*s0
      stM(lds_s, 0, n, w, wa[cti][reg] * t0 * e0);
      float bmul = wb[cti][reg] * t0;
      stM(lds_s, 2, n, w, bmul * e1x);
      stM(lds_s, 4, n, w, bmul * e1y);
      stM(lds_s, 6, n, w, bmul * e1z);
    }
  }

  // ---- prefetch wc/wd (consumed in phase 2b; hidden under stage 2a) ----
  float wc_[2][4], wd[2][4];
#pragma unroll
  for (int reg = 0; reg < 4; ++reg) {
    int n = r0 + (lg << 2) + reg;
    const float* tr = tp + (size_t)(R0 + n) * 256;
#pragma unroll
    for (int cti = 0; cti < 2; ++cti) {
      int w = (2 * ch + cti) * 16 + (lane & 15);
      wc_[cti][reg] = tr[128 + w];
      wd[cti][reg] = tr[192 + w];
    }
  }
  __syncthreads();

  // ---- stage 2a: WA on mA -> outS ; WB on mB_m -> outV[m] ----
  {
    BF2 B;
    bf16x8 ah[2], al[2];
    loadB(ws, 4, lane, ch, B);                   // W_lin_A
    ldM(lds_s, 0, arow, lane, ah, al);
    cluster(ah, al, B, outS);
    loadB(ws, 6, lane, ch, B);                   // W_lin_B (x3 reuse)
#pragma unroll
    for (int m = 0; m < 3; ++m) {
      ldM(lds_s, 2 + 2 * m, arow, lane, ah, al);
      cluster(ah, al, B, outV[m]);
    }
  }
  __syncthreads();

  // ---- phase 2b: kp*mD -> (0,1), kp*mC_m -> (2,3),(4,5),(6,7); tp from regs ----
#pragma unroll
  for (int reg = 0; reg < 4; ++reg) {
    int n = r0 + (lg << 2) + reg;
    const float* cr = cst + n * 6;
    float e0 = cr[0], e1x = cr[1], e1y = cr[2], e1z = cr[3], c2a = cr[4];
#pragma unroll
    for (int cti = 0; cti < 2; ++cti) {
      int w = (2 * ch + cti) * 16 + (lane & 15);
      float kv0 = c2a * v0v[0][cti][reg];
      float kv1 = c2a * v0v[1][cti][reg];
      float kv2 = c2a * v0v[2][cti][reg];
      stM(lds_s, 0, n, w,
          wd[cti][reg] * (kv0 * e1x + kv1 * e1y + kv2 * e1z) * 0.5773502691896258f);
      float wcv = wc_[cti][reg];
      stM(lds_s, 2, n, w, wcv * kv0 * e0);
      stM(lds_s, 4, n, w, wcv * kv1 * e0);
      stM(lds_s, 6, n, w, wcv * kv2 * e0);
    }
  }
  __syncthreads();

  // ---- stage 2b: WD on mD -> outS ; WC on mC_m -> outV[m] ----
  {
    BF2 B;
    bf16x8 ah[2], al[2];
    loadB(ws, 5, lane, ch, B);                   // W_lin_D
    ldM(lds_s, 0, arow, lane, ah, al);
    cluster(ah, al, B, outS);
    loadB(ws, 7, lane, ch, B);                   // W_lin_C (x3 reuse)
#pragma unroll
    for (int m = 0; m < 3; ++m) {
      ldM(lds_s, 2 + 2 * m, arow, lane, ah, al);
      cluster(ah, al, B, outV[m]);
    }
  }

  // ---- epilogue: bare store of own columns ----
#pragma unroll
  for (int reg = 0; reg < 4; ++reg) {
    int n = r0 + (lg << 2) + reg;
    float* orow = out + (size_t)(R0 + n) * 256;
#pragma unroll
    for (int cti = 0; cti < 2; ++cti) {
      int w = (2 * ch + cti) * 16 + (lane & 15);
      orow[w] = outS[cti][reg];
      float* vp = orow + 64 + 3 * w;
      vp[0] = outV[0][cti][reg];
      vp[1] = outV[1][cti][reg];
      vp[2] = outV[2][cti][reg];
    }
  }
}

extern "C" void kernel_launch(void* const* d_in, const int* in_sizes, int n_in,
                              void* d_out, int out_size, void* d_ws, size_t ws_size,
                              hipStream_t stream) {
  const float* x1   = (const float*)d_in[0];
  const float* edge = (const float*)d_in[1];
  const float* tp   = (const float*)d_in[2];
  const float* node = (const float*)d_in[3];
  short* ws = (short*)d_ws;  // 128 KiB
  int n = in_sizes[0] / 256;

  // mats: 0=W_sc_s 1=W_lin0_s 2=W_sc_v 3=W_lin0_v 4=W_lin_A 5=W_lin_D 6=W_lin_B 7=W_lin_C
  prep_w<<<16, 256, 0, stream>>>(
      (const float*)d_in[6], (const float*)d_in[4],
      (const float*)d_in[7], (const float*)d_in[5],
      (const float*)d_in[8], (const float*)d_in[9],
      (const float*)d_in[10], (const float*)d_in[11], ws);

  fused_tp<<<n / 32, 256, 0, stream>>>(x1, edge, tp, node, ws, (float*)d_out);
}